// Round 2
// baseline (203.871 us; speedup 1.0000x reference)
//
#include <hip/hip_runtime.h>

#define NROWS 384
#define DDIM  768
#define TILE  32
#define LDP   36   // padded LDS row (floats)
#define KSPLIT 4
#define KCHUNK (DDIM / KSPLIT)   // 192

// ---------------------------------------------------------------------------
// K1: partial GEMM with k-split. grid.z encodes (g, kc): g = z>>2 (0 = A half,
// 1 = B half), kc = z&3 (k-chunk). Partials accumulated into zeroed ws via
// HW fp32 atomics. b1 folded in by the kc==0 blocks of the A half.
//   A' row-major:  ws[i*768 + od]
//   B d-blocked :  ws[384*768 + ((od>>2)*384 + j)*4 + (od&3)]   (j = row i)
// ---------------------------------------------------------------------------
__global__ __launch_bounds__(64) void k1_gemm(
    const float* __restrict__ p, const float* __restrict__ W1,
    const float* __restrict__ b1, float* __restrict__ ws) {
  const int ib = blockIdx.x;        // i-tile  (0..11)
  const int ob = blockIdx.y;        // od-tile (0..23)
  const int g  = blockIdx.z >> 2;   // half
  const int kc = blockIdx.z & 3;    // k-chunk

  __shared__ float pT[TILE][LDP];   // pT[k][i]
  __shared__ float wT[TILE][LDP];   // wT[k][od]

  const int t  = threadIdx.x;
  const int i0 = (t & 7) * 4;
  const int o0 = (t >> 3) * 4;
  const int iBase = ib * TILE;
  const int oBase = ob * TILE;

  float acc[4][4] = {};

  const int kk = (t & 7) * 4;
  const int rr = t >> 3;

  const int kLo = kc * KCHUNK;
  for (int k0 = kLo; k0 < kLo + KCHUNK; k0 += TILE) {
    #pragma unroll
    for (int rp = 0; rp < TILE; rp += 8) {
      const int row = rr + rp;
      const float4 v = *(const float4*)&p[(size_t)(iBase + row) * DDIM + k0 + kk];
      pT[kk + 0][row] = v.x; pT[kk + 1][row] = v.y;
      pT[kk + 2][row] = v.z; pT[kk + 3][row] = v.w;
      const float4 w = *(const float4*)&W1[(size_t)(oBase + row) * (2 * DDIM) + g * DDIM + k0 + kk];
      wT[kk + 0][row] = w.x; wT[kk + 1][row] = w.y;
      wT[kk + 2][row] = w.z; wT[kk + 3][row] = w.w;
    }
    __syncthreads();

    #pragma unroll 8
    for (int k = 0; k < TILE; ++k) {
      float a[4], b[4];
      *(float4*)a = *(const float4*)&pT[k][i0];
      *(float4*)b = *(const float4*)&wT[k][o0];
      #pragma unroll
      for (int ii = 0; ii < 4; ++ii)
        #pragma unroll
        for (int oo = 0; oo < 4; ++oo)
          acc[ii][oo] = fmaf(a[ii], b[oo], acc[ii][oo]);
    }
    __syncthreads();
  }

  const int col = oBase + o0;
  if (g == 0) {
    float* A = ws;   // row-major [384][768]
    #pragma unroll
    for (int ii = 0; ii < 4; ++ii) {
      const int row = iBase + i0 + ii;
      #pragma unroll
      for (int oo = 0; oo < 4; ++oo) {
        float v = acc[ii][oo];
        if (kc == 0) v += b1[col + oo];
        unsafeAtomicAdd(&A[(size_t)row * DDIM + col + oo], v);
      }
    }
  } else {
    float* Bt = ws + (size_t)NROWS * DDIM;  // [192][384][4] d-blocked
    const int dg = col >> 2;                 // col % 4 == 0
    #pragma unroll
    for (int ii = 0; ii < 4; ++ii) {
      const int row = iBase + i0 + ii;
      #pragma unroll
      for (int oo = 0; oo < 4; ++oo)
        unsafeAtomicAdd(&Bt[((size_t)dg * NROWS + row) * 4 + oo], acc[ii][oo]);
    }
  }
}

// ---------------------------------------------------------------------------
// K2: logits[i][j][c] = sum_d tanh(A'[i][d] + B[j][d]) * W2[c][d] + b2[c]
// wave -> i (uniform, scalar loads for A'/W2), lane -> j.
// B read from the d-blocked layout: float4 per lane, consecutive lanes at
// consecutive 16B addresses -> fully coalesced, L1-resident per block.
// ---------------------------------------------------------------------------
__device__ __forceinline__ float fast_tanh(float s) {
  const float e = __builtin_amdgcn_exp2f(s * 2.88539008177793f);  // exp(2s)
  return 1.0f - 2.0f * __builtin_amdgcn_rcpf(e + 1.0f);
}

__global__ __launch_bounds__(256) void k2_fused(
    const float* __restrict__ ws, const float* __restrict__ W2,
    const float* __restrict__ b2, float* __restrict__ out) {
  const int lane = threadIdx.x & 63;
  const int wave = threadIdx.x >> 6;
  const int i = __builtin_amdgcn_readfirstlane(blockIdx.x * 4 + wave);
  const int j = blockIdx.y * 64 + lane;

  const float*  __restrict__ Ap  = ws + (size_t)i * DDIM;                 // uniform
  const float4* __restrict__ Bt  = (const float4*)(ws + (size_t)NROWS * DDIM);
  const float*  __restrict__ w0p = W2;                                    // uniform
  const float*  __restrict__ w1p = W2 + DDIM;                             // uniform

  float acc0[4] = {}, acc1[4] = {};

  #pragma unroll 4
  for (int dg = 0; dg < DDIM / 4; ++dg) {
    const float4 b4  = Bt[(size_t)dg * NROWS + j];        // coalesced per-lane
    const float4 a4  = *(const float4*)&Ap[dg * 4];       // scalar (uniform)
    const float4 w04 = *(const float4*)&w0p[dg * 4];
    const float4 w14 = *(const float4*)&w1p[dg * 4];

    float t;
    t = fast_tanh(a4.x + b4.x); acc0[0] = fmaf(t, w04.x, acc0[0]); acc1[0] = fmaf(t, w14.x, acc1[0]);
    t = fast_tanh(a4.y + b4.y); acc0[1] = fmaf(t, w04.y, acc0[1]); acc1[1] = fmaf(t, w14.y, acc1[1]);
    t = fast_tanh(a4.z + b4.z); acc0[2] = fmaf(t, w04.z, acc0[2]); acc1[2] = fmaf(t, w14.z, acc1[2]);
    t = fast_tanh(a4.w + b4.w); acc0[3] = fmaf(t, w04.w, acc0[3]); acc1[3] = fmaf(t, w14.w, acc1[3]);
  }

  float2 r;
  r.x = (acc0[0] + acc0[1]) + (acc0[2] + acc0[3]) + b2[0];
  r.y = (acc1[0] + acc1[1]) + (acc1[2] + acc1[3]) + b2[1];
  *(float2*)&out[((size_t)i * NROWS + j) * 2] = r;
}

// ---------------------------------------------------------------------------
extern "C" void kernel_launch(void* const* d_in, const int* in_sizes, int n_in,
                              void* d_out, int out_size, void* d_ws, size_t ws_size,
                              hipStream_t stream) {
  const float* p  = (const float*)d_in[0];   // [384, 768]
  const float* W1 = (const float*)d_in[1];   // [768, 1536]
  const float* b1 = (const float*)d_in[2];   // [768]
  const float* W2 = (const float*)d_in[3];   // [2, 768]
  const float* b2 = (const float*)d_in[4];   // [2]
  float* out = (float*)d_out;                // [384, 384, 2]
  float* ws  = (float*)d_ws;                 // A' (384*768) then Btb (384*768)

  // zero the accumulation workspace (re-poisoned to 0xAA before every call)
  hipMemsetAsync(ws, 0, (size_t)2 * NROWS * DDIM * sizeof(float), stream);

  dim3 g1(NROWS / TILE, DDIM / TILE, 2 * KSPLIT);   // 12 x 24 x 8
  k1_gemm<<<g1, 64, 0, stream>>>(p, W1, b1, ws);

  dim3 g2(NROWS / 4, NROWS / 64);                   // 96 x 6
  k2_fused<<<g2, 256, 0, stream>>>(ws, W2, b2, out);
}

// Round 3
// 184.579 us; speedup vs baseline: 1.1045x; 1.1045x over previous
//
#include <hip/hip_runtime.h>

#define NROWS 384
#define DDIM  768
#define L2E2  2.885390081777927f   // 2 * log2(e): exp(2s) = exp2(L2E2 * s)

// ws layout (floats): pTb [192 kg][384 i][4]   at 0
//                     A2b [192 dg][384 i][4]   at 294912   (prescaled A'+b1)
//                     Bt2 [192 dg][384 j][4]   at 589824   (prescaled B)
#define WS_A2 (NROWS * DDIM)
#define WS_BT (2 * NROWS * DDIM)

// ---------------------------------------------------------------------------
// K0: d-blocked transpose of p: pTb[(k>>2)*384 + i][k&3] = p[i][k]
// Coalesced float4 reads; 16B scattered writes (1.1 MB, L2-absorbed).
// ---------------------------------------------------------------------------
__global__ __launch_bounds__(256) void k0_transform(
    const float* __restrict__ p, float* __restrict__ ws) {
  const int flat = blockIdx.x * 256 + threadIdx.x;   // 73728 float4s total
  const int i  = flat / (DDIM / 4);
  const int kg = flat % (DDIM / 4);
  const float4 v = ((const float4*)p)[flat];
  ((float4*)ws)[kg * NROWS + i] = v;
}

// ---------------------------------------------------------------------------
// K1: C[i][c] = sum_k p[i][k] * W1[c%768][(c/768)*768 + k]
// wave -> 8 consecutive c (W1 rows wave-uniform -> scalar loads),
// lane -> i (coalesced float4 reads of pTb). 32 FMA per vector load.
// Outputs prescaled by L2E2, b1 folded into the A half, both halves stored
// d-blocked [dg][row][4] for K2.
// ---------------------------------------------------------------------------
__global__ __launch_bounds__(256) void k1_gemm(
    const float* __restrict__ ws_in, const float* __restrict__ W1,
    const float* __restrict__ b1, float* __restrict__ ws) {
  const int lane = threadIdx.x & 63;
  const int wave = threadIdx.x >> 6;
  const int row  = blockIdx.y * 64 + lane;                        // i in [0,384)
  const int c0   = __builtin_amdgcn_readfirstlane(blockIdx.x * 32 + wave * 8);
  const int g    = c0 >= DDIM;          // 0 = A half, 1 = B half
  const int o0   = c0 - g * DDIM;       // W1 row base, [0,768), o0 % 8 == 0

  const float4* __restrict__ pT4 = (const float4*)ws_in;          // [192][384]
  const float*  __restrict__ wb  = W1 + (size_t)o0 * (2 * DDIM) + g * DDIM;

  float acc[8] = {};

  #pragma unroll 2
  for (int kg = 0; kg < DDIM / 4; ++kg) {
    const float4 pv = pT4[kg * NROWS + row];        // coalesced, L1/L2-resident
    #pragma unroll
    for (int cc = 0; cc < 8; ++cc) {
      const float4 w4 = *(const float4*)&wb[(size_t)cc * (2 * DDIM) + 4 * kg];  // s_load
      acc[cc] = fmaf(pv.x, w4.x, acc[cc]);
      acc[cc] = fmaf(pv.y, w4.y, acc[cc]);
      acc[cc] = fmaf(pv.z, w4.z, acc[cc]);
      acc[cc] = fmaf(pv.w, w4.w, acc[cc]);
    }
  }

  float* __restrict__ dst = ws + (g ? WS_BT : WS_A2);
  #pragma unroll
  for (int cc = 0; cc < 8; ++cc) {
    const int o = o0 + cc;
    float v = acc[cc];
    if (!g) v += b1[o];                 // fold bias into A half
    v *= L2E2;                          // fold tanh prescale
    dst[((size_t)(o >> 2) * NROWS + row) * 4 + (o & 3)] = v;
  }
}

// ---------------------------------------------------------------------------
// K2: logits[i][j][c] = (sumW_c - 2 * sum_d W2[c][d] * r_ijd) + b2[c]
//     with r = rcp(exp2(A2[i][d] + Bt2[j][d]) + 1)   (prescale folded in K1)
// wave -> 2 i rows (uniform scalar loads), lane -> j (coalesced Bt2 float4).
// 6 VALU insts per element; Bt2 shared across block's 4 waves via L1.
// ---------------------------------------------------------------------------
__global__ __launch_bounds__(256) void k2_fused(
    const float* __restrict__ ws, const float* __restrict__ W2,
    const float* __restrict__ b2, float* __restrict__ out) {
  const int lane = threadIdx.x & 63;
  const int wave = threadIdx.x >> 6;
  const int i0 = __builtin_amdgcn_readfirstlane((blockIdx.x * 4 + wave) * 2);
  const int i1 = i0 + 1;
  const int j  = blockIdx.y * 64 + lane;

  const float4* __restrict__ A4 = (const float4*)(ws + WS_A2);
  const float4* __restrict__ B4 = (const float4*)(ws + WS_BT);
  const float*  __restrict__ w0 = W2;          // uniform
  const float*  __restrict__ w1 = W2 + DDIM;   // uniform

  // per-wave sumW via strided partial + butterfly reduce
  float sw0 = 0.f, sw1 = 0.f;
  #pragma unroll
  for (int d = 0; d < DDIM; d += 64) { sw0 += w0[d + lane]; sw1 += w1[d + lane]; }
  #pragma unroll
  for (int off = 32; off; off >>= 1) {
    sw0 += __shfl_xor(sw0, off);
    sw1 += __shfl_xor(sw1, off);
  }

  float a00[4] = {}, a01[4] = {}, a10[4] = {}, a11[4] = {};

  for (int dg = 0; dg < DDIM / 4; ++dg) {
    const float4 b4  = B4[dg * NROWS + j];       // coalesced per-lane
    const float4 av0 = A4[dg * NROWS + i0];      // uniform (scalar)
    const float4 av1 = A4[dg * NROWS + i1];      // uniform (scalar)
    const float4 w04 = *(const float4*)&w0[dg * 4];
    const float4 w14 = *(const float4*)&w1[dg * 4];

    float e, r;
    e = __builtin_amdgcn_exp2f(av0.x + b4.x); r = __builtin_amdgcn_rcpf(e + 1.f);
    a00[0] = fmaf(w04.x, r, a00[0]); a01[0] = fmaf(w14.x, r, a01[0]);
    e = __builtin_amdgcn_exp2f(av1.x + b4.x); r = __builtin_amdgcn_rcpf(e + 1.f);
    a10[0] = fmaf(w04.x, r, a10[0]); a11[0] = fmaf(w14.x, r, a11[0]);

    e = __builtin_amdgcn_exp2f(av0.y + b4.y); r = __builtin_amdgcn_rcpf(e + 1.f);
    a00[1] = fmaf(w04.y, r, a00[1]); a01[1] = fmaf(w14.y, r, a01[1]);
    e = __builtin_amdgcn_exp2f(av1.y + b4.y); r = __builtin_amdgcn_rcpf(e + 1.f);
    a10[1] = fmaf(w04.y, r, a10[1]); a11[1] = fmaf(w14.y, r, a11[1]);

    e = __builtin_amdgcn_exp2f(av0.z + b4.z); r = __builtin_amdgcn_rcpf(e + 1.f);
    a00[2] = fmaf(w04.z, r, a00[2]); a01[2] = fmaf(w14.z, r, a01[2]);
    e = __builtin_amdgcn_exp2f(av1.z + b4.z); r = __builtin_amdgcn_rcpf(e + 1.f);
    a10[2] = fmaf(w04.z, r, a10[2]); a11[2] = fmaf(w14.z, r, a11[2]);

    e = __builtin_amdgcn_exp2f(av0.w + b4.w); r = __builtin_amdgcn_rcpf(e + 1.f);
    a00[3] = fmaf(w04.w, r, a00[3]); a01[3] = fmaf(w14.w, r, a01[3]);
    e = __builtin_amdgcn_exp2f(av1.w + b4.w); r = __builtin_amdgcn_rcpf(e + 1.f);
    a10[3] = fmaf(w04.w, r, a10[3]); a11[3] = fmaf(w14.w, r, a11[3]);
  }

  const float s00 = (a00[0] + a00[1]) + (a00[2] + a00[3]);
  const float s01 = (a01[0] + a01[1]) + (a01[2] + a01[3]);
  const float s10 = (a10[0] + a10[1]) + (a10[2] + a10[3]);
  const float s11 = (a11[0] + a11[1]) + (a11[2] + a11[3]);

  float2 r0, r1;
  r0.x = fmaf(-2.f, s00, sw0) + b2[0];
  r0.y = fmaf(-2.f, s01, sw1) + b2[1];
  r1.x = fmaf(-2.f, s10, sw0) + b2[0];
  r1.y = fmaf(-2.f, s11, sw1) + b2[1];
  *(float2*)&out[((size_t)i0 * NROWS + j) * 2] = r0;
  *(float2*)&out[((size_t)i1 * NROWS + j) * 2] = r1;
}

// ---------------------------------------------------------------------------
extern "C" void kernel_launch(void* const* d_in, const int* in_sizes, int n_in,
                              void* d_out, int out_size, void* d_ws, size_t ws_size,
                              hipStream_t stream) {
  const float* p  = (const float*)d_in[0];   // [384, 768]
  const float* W1 = (const float*)d_in[1];   // [768, 1536]
  const float* b1 = (const float*)d_in[2];   // [768]
  const float* W2 = (const float*)d_in[3];   // [2, 768]
  const float* b2 = (const float*)d_in[4];   // [2]
  float* out = (float*)d_out;                // [384, 384, 2]
  float* ws  = (float*)d_ws;

  k0_transform<<<dim3((NROWS * DDIM / 4) / 256), 256, 0, stream>>>(p, ws);

  dim3 g1(2 * DDIM / 32, NROWS / 64);        // 48 x 6
  k1_gemm<<<g1, 256, 0, stream>>>(ws, W1, b1, ws);

  dim3 g2(NROWS / 8, NROWS / 64);            // 48 x 6
  k2_fused<<<g2, 256, 0, stream>>>(ws, W2, b2, out);
}